// Round 17
// baseline (975.698 us; speedup 1.0000x reference)
//
#include <hip/hip_runtime.h>

#define NB    8       // batches
#define NP    4096    // points per batch
#define KNN   20      // neighbors
#define COUT  64      // output channels
#define S     8       // split lanes per query (occupancy play)
#define BLK   256     // threads per block (4 waves)
#define QPB   (BLK / S)          // 32 queries per block
#define BPB   (NP / QPB)         // 128 blocks per batch
#define NBLK1 (NB * BPB)         // 1024 blocks -> 3 blocks/CU (48 KB LDS)
#define NBLK2 ((NB * NP * 4) / BLK)   // 512 blocks (4 threads per query)
#define NMOM  14
#define LCAP  32      // padded list length for bitonic merge
#define FBIG  3.402823466e38f

typedef unsigned long long u64;
typedef unsigned int u32;

// strict-< sorted insert (ascending), insert-after-equals == lax.top_k's
// lowest-index-first tie-break (verified rounds 4/6/8/11/12/16). FBIG -> no-op.
__device__ __forceinline__ void ins20(float d, u32 mi,
                                      float* __restrict__ bd,
                                      u32* __restrict__ bi) {
#pragma unroll
    for (int j = KNN - 1; j >= 1; --j) {
        const bool sh  = d < bd[j - 1];
        const bool in_ = !sh && (d < bd[j]);
        bi[j] = sh ? bi[j - 1] : (in_ ? mi : bi[j]);
        bd[j] = fminf(fmaxf(bd[j - 1], d), bd[j]);   // med3
    }
    if (d < bd[0]) { bi[0] = mi; bd[0] = d; }
}

// ---------------- Kernel 1: KNN (S=8, 48 KB LDS, r16 innards) ------------
__global__ __launch_bounds__(BLK, 3)
void knn_kernel(const float* __restrict__ pos,
                unsigned short* __restrict__ idx_out,
                float* __restrict__ mom) {
    __shared__ float sx[NP], sy[NP], sz[NP];       // 48 KB -> 3 blocks/CU

    const int b = blockIdx.x / BPB;
    const int t = threadIdx.x;
    const int s = t & (S - 1);                     // my split lane (0..7)
    const int n = (blockIdx.x % BPB) * QPB + (t >> 3);   // my query
    const float* pb = pos + (size_t)b * NP * 3;

    for (int i = t; i < NP; i += BLK) {
        sx[i] = pb[3 * i + 0];
        sy[i] = pb[3 * i + 1];
        sz[i] = pb[3 * i + 2];
    }
    __syncthreads();

    const float qx = sx[n], qy = sy[n], qz = sz[n];
    // reference op sequence: sq = ((x*x)+(y*y))+(z*z), plain rounded muls
    const float qsq = __fadd_rn(__fadd_rn(__fmul_rn(qx, qx), __fmul_rn(qy, qy)),
                                __fmul_rn(qz, qz));

    float bd[KNN];
    u32   bi[KNN];
#pragma unroll
    for (int j = 0; j < KNN; ++j) { bd[j] = FBIG; bi[j] = 0xFFFu; }
    float gb = FBIG;                               // group-min bound (r12/16-verified)
    float p0d = 0.f, p1d = 0.f, p2d = 0.f, p3d = 0.f;
    u32   p0i = 0, p1i = 0, p2i = 0, p3i = 0;
    int   cnt = 0;

#pragma unroll 2
    for (int i = 0; i < NP / S; ++i) {
        const int m = (i << 3) | s;                // 8 consecutive addrs: broadcast
        const float cx = sx[m], cy = sy[m], cz = sz[m];
        const float csq = __fadd_rn(
            __fadd_rn(__fmul_rn(cx, cx), __fmul_rn(cy, cy)), __fmul_rn(cz, cz));
        const float dot = fmaf(qz, cz, fmaf(qy, cy, __fmul_rn(qx, cx)));
        const float d2  = __fsub_rn(__fadd_rn(qsq, csq), __fmul_rn(2.0f, dot));
        // <=: rejection requires 20 STRICTLY better witnesses (index-free);
        // boundary cases flow through own-lane ins20 (exact). (r12/16-verified)
        const bool acc = (m != n) && (d2 <= gb);
        const bool a0 = acc && (cnt == 0), a1 = acc && (cnt == 1);
        const bool a2 = acc && (cnt == 2), a3 = acc && (cnt == 3);
        p0d = a0 ? d2 : p0d;  p0i = a0 ? (u32)m : p0i;
        p1d = a1 ? d2 : p1d;  p1i = a1 ? (u32)m : p1i;
        p2d = a2 ? d2 : p2d;  p2i = a2 ? (u32)m : p2i;
        p3d = a3 ? d2 : p3d;  p3i = a3 ? (u32)m : p3i;
        cnt += (int)acc;
        if (__ballot(cnt == 4)) {                  // amortized wave-wide flush
            ins20(cnt >= 1 ? p0d : FBIG, p0i, bd, bi);
            ins20(cnt >= 2 ? p1d : FBIG, p1i, bd, bi);
            ins20(cnt >= 3 ? p2d : FBIG, p2i, bd, bi);
            ins20(cnt >= 4 ? p3d : FBIG, p3i, bd, bi);
            cnt = 0;
            float g = bd[KNN - 1];                 // refresh group bound (8 lanes)
            g = fminf(g, __shfl_xor(g, 1));
            g = fminf(g, __shfl_xor(g, 2));
            g = fminf(g, __shfl_xor(g, 4));
            gb = g;
        }
    }
    // drain pending
    ins20(cnt >= 1 ? p0d : FBIG, p0i, bd, bi);
    ins20(cnt >= 2 ? p1d : FBIG, p1i, bd, bi);
    ins20(cnt >= 3 ? p2d : FBIG, p2i, bd, bi);
    ins20(cnt >= 4 ? p3d : FBIG, p3i, bd, bi);

    // build merge keys: order-preserving float->uint flip,
    // idx in low 12 bits = lowest-index-first ties (verified r7/8/11/12/16)
    u64 key[LCAP];
#pragma unroll
    for (int j = 0; j < KNN; ++j) {
        u32 fb = __float_as_uint(bd[j]);
        fb ^= (u32)((int)fb >> 31) | 0x80000000u;
        key[j] = ((u64)fb << 12) | bi[j];
    }
#pragma unroll
    for (int j = KNN; j < LCAP; ++j) key[j] = ~0ull;

    // merge 8 split lists across lanes: same verified half-cleaner code,
    // one extra round (r = 1, 2, 4)
#pragma unroll
    for (int r = 1; r <= 4; r <<= 1) {
#pragma unroll
        for (int j = 0; j < LCAP / 2; ++j) {
            const int k2 = LCAP - 1 - j;
            const u64 pa = (u64)__shfl_xor((long long)key[k2], r);
            const u64 pc = (u64)__shfl_xor((long long)key[j],  r);
            key[j]  = key[j]  < pa ? key[j]  : pa;
            key[k2] = key[k2] < pc ? key[k2] : pc;
        }
#pragma unroll
        for (int d = 16; d >= 1; d >>= 1) {
#pragma unroll
            for (int j = 0; j < LCAP; ++j) {
                if ((j & d) == 0) {
                    const u64 x = key[j], y = key[j + d];
                    key[j]     = x < y ? x : y;
                    key[j + d] = x < y ? y : x;
                }
            }
        }
    }

    // static-j epilogue (verified; no dynamic reg indexing)
    unsigned short* ip = idx_out + ((size_t)b * NP + n) * KNN;
    float s1x = 0, s1y = 0, s1z = 0, s1d = 0;
    float mxx = 0, mxy = 0, mxz = 0, mxd = 0;
    float myy = 0, myz = 0, myd = 0;
    float mzz = 0, mzd = 0, mdd = 0;
#pragma unroll
    for (int j = 0; j < KNN; ++j) {
        const int m = (int)(key[j] & 0xFFFull);
        if ((j & 7) == s) ip[j] = (unsigned short)m;   // one lane per j
        const float dx = __fsub_rn(sx[m], qx);
        const float dy = __fsub_rn(sy[m], qy);
        const float dz = __fsub_rn(sz[m], qz);
        const float dd = sqrtf(__fadd_rn(
            __fadd_rn(__fmul_rn(dx, dx), __fmul_rn(dy, dy)), __fmul_rn(dz, dz)));
        s1x += dx; s1y += dy; s1z += dz; s1d += dd;
        mxx += dx * dx; mxy += dx * dy; mxz += dx * dz; mxd += dx * dd;
        myy += dy * dy; myz += dy * dz; myd += dy * dd;
        mzz += dz * dz; mzd += dz * dd; mdd += dd * dd;
    }
    {
        // every query counted 8x (once per split lane) -> exact /8 after reduce
        float vals[NMOM] = {s1x, s1y, s1z, s1d,
                            mxx, mxy, mxz, mxd, myy, myz, myd, mzz, mzd, mdd};
#pragma unroll
        for (int tt = 0; tt < NMOM; ++tt) {
            float v = vals[tt];
#pragma unroll
            for (int off = 32; off > 0; off >>= 1) v += __shfl_down(v, off);
            if ((t & 63) == 0) atomicAdd(&mom[tt], v * 0.125f);
        }
    }
}

// ---------------- Kernel 2: round-8/11/12/16 verbatim --------------------
__global__ __launch_bounds__(BLK)
void out_kernel(const float* __restrict__ pos,
                const float* __restrict__ W,
                const float* __restrict__ bias,
                const float* __restrict__ gamma,
                const float* __restrict__ beta,
                const unsigned short* __restrict__ idx_in,
                const float* __restrict__ mom,
                float* __restrict__ out) {
    __shared__ float sWp[COUT][4];
    __shared__ float sbp[COUT];

    if (threadIdx.x < COUT) {
        const int o = threadIdx.x;
        double S1[4], s2v[10];
#pragma unroll
        for (int tt = 0; tt < 4; ++tt)  S1[tt]  = (double)mom[tt];
#pragma unroll
        for (int tt = 0; tt < 10; ++tt) s2v[tt] = (double)mom[4 + tt];
        const double M = (double)NB * NP * KNN;
        double mean[4];
#pragma unroll
        for (int c = 0; c < 4; ++c) mean[c] = S1[c] / M;
        double E2[4][4];
        E2[0][0] = s2v[0]; E2[0][1] = E2[1][0] = s2v[1];
        E2[0][2] = E2[2][0] = s2v[2]; E2[0][3] = E2[3][0] = s2v[3];
        E2[1][1] = s2v[4]; E2[1][2] = E2[2][1] = s2v[5];
        E2[1][3] = E2[3][1] = s2v[6];
        E2[2][2] = s2v[7]; E2[2][3] = E2[3][2] = s2v[8];
        E2[3][3] = s2v[9];
        double w[4];
#pragma unroll
        for (int c = 0; c < 4; ++c) w[c] = (double)W[o * 4 + c];
        const double bo = (double)bias[o];
        double mu = bo;
#pragma unroll
        for (int c = 0; c < 4; ++c) mu += w[c] * mean[c];
        double var = 0.0;
#pragma unroll
        for (int c = 0; c < 4; ++c)
#pragma unroll
            for (int c2 = 0; c2 < 4; ++c2)
                var += w[c] * w[c2] * (E2[c][c2] / M - mean[c] * mean[c2]);
        const double scale = (double)gamma[o] / sqrt(var + 1e-5);
#pragma unroll
        for (int c = 0; c < 4; ++c) sWp[o][c] = (float)(w[c] * scale);
        sbp[o] = (float)((bo - mu) * scale + (double)beta[o]);
    }
    __syncthreads();

    const int t  = threadIdx.x;
    const int gq = blockIdx.x * (BLK / 4) + (t >> 2);  // global query
    const int b  = gq / NP, n = gq % NP;
    const int c0 = (t & 3) * 16;                       // my 16 channels
    const float* pb = pos + (size_t)b * NP * 3;
    const float qx = pb[3 * n], qy = pb[3 * n + 1], qz = pb[3 * n + 2];

    float fx[KNN], fy[KNN], fz[KNN], fd[KNN];
    const unsigned short* ip = idx_in + (size_t)gq * KNN;
#pragma unroll
    for (int j = 0; j < KNN; ++j) {
        const int m = ip[j];
        const float dx = __fsub_rn(pb[3 * m], qx);
        const float dy = __fsub_rn(pb[3 * m + 1], qy);
        const float dz = __fsub_rn(pb[3 * m + 2], qz);
        fx[j] = dx; fy[j] = dy; fz[j] = dz;
        fd[j] = sqrtf(__fadd_rn(
            __fadd_rn(__fmul_rn(dx, dx), __fmul_rn(dy, dy)), __fmul_rn(dz, dz)));
    }

    float* ob = out + (size_t)gq * COUT + c0;
    const float inv = 1.0f / (float)KNN;
#pragma unroll
    for (int o = 0; o < 16; o += 4) {
        float acc[4];
#pragma unroll
        for (int qq = 0; qq < 4; ++qq) {
            const float w0 = sWp[c0 + o + qq][0], w1 = sWp[c0 + o + qq][1];
            const float w2 = sWp[c0 + o + qq][2], w3 = sWp[c0 + o + qq][3];
            const float bb = sbp[c0 + o + qq];
            float a = 0.f;
#pragma unroll
            for (int j = 0; j < KNN; ++j) {
                float y = fmaf(fx[j], w0,
                          fmaf(fy[j], w1, fmaf(fz[j], w2, fmaf(fd[j], w3, bb))));
                a += fmaxf(y, 0.f);
            }
            acc[qq] = a * inv;
        }
        float4 p = {acc[0], acc[1], acc[2], acc[3]};
        *reinterpret_cast<float4*>(ob + o) = p;
    }
}

extern "C" void kernel_launch(void* const* d_in, const int* in_sizes, int n_in,
                              void* d_out, int out_size, void* d_ws, size_t ws_size,
                              hipStream_t stream) {
    (void)in_sizes; (void)n_in; (void)out_size; (void)ws_size;
    const float* pos   = (const float*)d_in[1];   // d_in[0] = x (unused by math)
    const float* W     = (const float*)d_in[2];
    const float* bias  = (const float*)d_in[3];
    const float* gamma = (const float*)d_in[4];
    const float* beta  = (const float*)d_in[5];
    float* out = (float*)d_out;

    float* mom = (float*)d_ws;                                   // 14 floats
    unsigned short* idxws = (unsigned short*)((char*)d_ws + 64); // 1.31 MB

    hipMemsetAsync(mom, 0, NMOM * sizeof(float), stream);
    knn_kernel<<<NBLK1, BLK, 0, stream>>>(pos, idxws, mom);
    out_kernel<<<NBLK2, BLK, 0, stream>>>(pos, W, bias, gamma, beta,
                                          idxws, mom, out);
}

// Round 18
// 599.687 us; speedup vs baseline: 1.6270x; 1.6270x over previous
//
#include <hip/hip_runtime.h>

#define NB    8       // batches
#define NP    4096    // points per batch
#define KNN   20      // neighbors
#define COUT  64      // output channels
#define S     4       // candidate splits per query (r16-verified config)
#define BLK   256     // threads per block (4 waves)
#define QPB   (BLK / S)          // 64 queries per block
#define BPB   (NP / QPB)         // 64 blocks per batch
#define NBLK1 (NB * BPB)         // 512 blocks
#define NBLK2 ((NB * NP * 4) / BLK)   // 512 blocks (4 threads per query)
#define NMOM  14
#define LCAP  32      // padded list length for bitonic merge
#define FBIG  3.402823466e38f

typedef unsigned long long u64;
typedef unsigned int u32;

// strict-< sorted insert (ascending), insert-after-equals == lax.top_k's
// lowest-index-first tie-break (verified rounds 4/6/8/11/12/16). FBIG -> no-op.
__device__ __forceinline__ void ins20(float d, u32 mi,
                                      float* __restrict__ bd,
                                      u32* __restrict__ bi) {
#pragma unroll
    for (int j = KNN - 1; j >= 1; --j) {
        const bool sh  = d < bd[j - 1];
        const bool in_ = !sh && (d < bd[j]);
        bi[j] = sh ? bi[j - 1] : (in_ ? mi : bi[j]);
        bd[j] = fminf(fmaxf(bd[j - 1], d), bd[j]);   // med3
    }
    if (d < bd[0]) { bi[0] = mi; bd[0] = d; }
}

// ---------------- Kernel 1: KNN (r16 + certified sample bound) -----------
__global__ __launch_bounds__(BLK, 2)
void knn_kernel(const float* __restrict__ pos,
                unsigned short* __restrict__ idx_out,
                float* __restrict__ mom) {
    __shared__ float4 sp[NP];                      // 64 KB: (x, y, z, csq)

    const int b = blockIdx.x / BPB;
    const int t = threadIdx.x;
    const int s = t & (S - 1);                     // my split
    const int n = (blockIdx.x % BPB) * QPB + (t >> 2);   // my query
    const float* pb = pos + (size_t)b * NP * 3;

    // stage pos[b]; csq computed with the reference's exact op sequence
    for (int i = t; i < NP; i += BLK) {
        const float x = pb[3 * i], y = pb[3 * i + 1], z = pb[3 * i + 2];
        const float csq = __fadd_rn(
            __fadd_rn(__fmul_rn(x, x), __fmul_rn(y, y)), __fmul_rn(z, z));
        sp[i] = make_float4(x, y, z, csq);
    }
    __syncthreads();

    const float4 q = sp[n];                        // qx,qy,qz,qsq (same bits)

    // ---- sample phase: tight certified initial bound ----
    // Each lane: top-5 d2 over every-4th of its 1024 candidates (256 samples,
    // self excluded). Pooled over the 4 group lanes: 20 distinct non-self
    // elements <= gb0 = group-max of lane 5th-best => rejecting d2 > gb0 is
    // provably safe (20 strictly-better witnesses), index-independent.
    float sd0 = FBIG, sd1 = FBIG, sd2 = FBIG, sd3 = FBIG, sd4 = FBIG;
#pragma unroll 4
    for (int i = 0; i < NP / S; i += 4) {
        const int m = (i << 2) | s;
        const float4 c = sp[m];
        const float dot = fmaf(q.z, c.z, fmaf(q.y, c.y, __fmul_rn(q.x, c.x)));
        const float d2  = __fsub_rn(__fadd_rn(q.w, c.w), __fmul_rn(2.0f, dot));
        if (m != n && d2 < sd4) {                  // 5-deep med3 insert (values)
            sd4 = fminf(fmaxf(sd3, d2), sd4);
            sd3 = fminf(fmaxf(sd2, d2), sd3);
            sd2 = fminf(fmaxf(sd1, d2), sd2);
            sd1 = fminf(fmaxf(sd0, d2), sd1);
            sd0 = fminf(sd0, d2);
        }
    }
    float gb = sd4;                                // my 5th-smallest sample
    gb = fmaxf(gb, __shfl_xor(gb, 1));             // group-max -> certified-20
    gb = fmaxf(gb, __shfl_xor(gb, 2));

    float bd[KNN];
    u32   bi[KNN];
#pragma unroll
    for (int j = 0; j < KNN; ++j) { bd[j] = FBIG; bi[j] = 0xFFFu; }
    float p0d = 0.f, p1d = 0.f, p2d = 0.f, p3d = 0.f;
    u32   p0i = 0, p1i = 0, p2i = 0, p3i = 0;
    int   cnt = 0;

#pragma unroll 2
    for (int i = 0; i < NP / S; ++i) {
        const int m = (i << 2) | s;
        const float4 c = sp[m];                    // 4 distinct addrs: broadcast
        const float dot = fmaf(q.z, c.z, fmaf(q.y, c.y, __fmul_rn(q.x, c.x)));
        const float d2  = __fsub_rn(__fadd_rn(q.w, c.w), __fmul_rn(2.0f, dot));
        // <=: rejection requires 20 STRICTLY better witnesses (index-free);
        // boundary cases flow through own-lane ins20 (exact). (r12/16-verified)
        const bool acc = (m != n) && (d2 <= gb);
        const bool a0 = acc && (cnt == 0), a1 = acc && (cnt == 1);
        const bool a2 = acc && (cnt == 2), a3 = acc && (cnt == 3);
        p0d = a0 ? d2 : p0d;  p0i = a0 ? (u32)m : p0i;
        p1d = a1 ? d2 : p1d;  p1i = a1 ? (u32)m : p1i;
        p2d = a2 ? d2 : p2d;  p2i = a2 ? (u32)m : p2i;
        p3d = a3 ? d2 : p3d;  p3i = a3 ? (u32)m : p3i;
        cnt += (int)acc;
        if (__ballot(cnt == 4)) {                  // amortized wave-wide flush
            ins20(cnt >= 1 ? p0d : FBIG, p0i, bd, bi);
            ins20(cnt >= 2 ? p1d : FBIG, p1i, bd, bi);
            ins20(cnt >= 3 ? p2d : FBIG, p2i, bd, bi);
            ins20(cnt >= 4 ? p3d : FBIG, p3i, bd, bi);
            cnt = 0;
            float g = bd[KNN - 1];                 // refresh group bound
            g = fminf(g, __shfl_xor(g, 1));
            g = fminf(g, __shfl_xor(g, 2));
            gb = fminf(gb, g);                     // NEVER loosen below sample bound
        }
    }
    // drain pending
    ins20(cnt >= 1 ? p0d : FBIG, p0i, bd, bi);
    ins20(cnt >= 2 ? p1d : FBIG, p1i, bd, bi);
    ins20(cnt >= 3 ? p2d : FBIG, p2i, bd, bi);
    ins20(cnt >= 4 ? p3d : FBIG, p3i, bd, bi);

    // build merge keys: order-preserving float->uint flip,
    // idx in low 12 bits = lowest-index-first ties (verified r7/8/11/12/16)
    u64 key[LCAP];
#pragma unroll
    for (int j = 0; j < KNN; ++j) {
        u32 fb = __float_as_uint(bd[j]);
        fb ^= (u32)((int)fb >> 31) | 0x80000000u;
        key[j] = ((u64)fb << 12) | bi[j];
    }
#pragma unroll
    for (int j = KNN; j < LCAP; ++j) key[j] = ~0ull;

    // merge 4 split lists across lanes (verified bitonic merge)
#pragma unroll
    for (int r = 1; r <= 2; r <<= 1) {
#pragma unroll
        for (int j = 0; j < LCAP / 2; ++j) {
            const int k2 = LCAP - 1 - j;
            const u64 pa = (u64)__shfl_xor((long long)key[k2], r);
            const u64 pc = (u64)__shfl_xor((long long)key[j],  r);
            key[j]  = key[j]  < pa ? key[j]  : pa;
            key[k2] = key[k2] < pc ? key[k2] : pc;
        }
#pragma unroll
        for (int d = 16; d >= 1; d >>= 1) {
#pragma unroll
            for (int j = 0; j < LCAP; ++j) {
                if ((j & d) == 0) {
                    const u64 x = key[j], y = key[j + d];
                    key[j]     = x < y ? x : y;
                    key[j + d] = x < y ? y : x;
                }
            }
        }
    }

    // static-j epilogue (verified; no dynamic reg indexing)
    unsigned short* ip = idx_out + ((size_t)b * NP + n) * KNN;
    float s1x = 0, s1y = 0, s1z = 0, s1d = 0;
    float mxx = 0, mxy = 0, mxz = 0, mxd = 0;
    float myy = 0, myz = 0, myd = 0;
    float mzz = 0, mzd = 0, mdd = 0;
#pragma unroll
    for (int j = 0; j < KNN; ++j) {
        const int m = (int)(key[j] & 0xFFFull);
        if ((j & 3) == s) ip[j] = (unsigned short)m;   // one lane per j
        const float4 c = sp[m];
        const float dx = __fsub_rn(c.x, q.x);
        const float dy = __fsub_rn(c.y, q.y);
        const float dz = __fsub_rn(c.z, q.z);
        const float dd = sqrtf(__fadd_rn(
            __fadd_rn(__fmul_rn(dx, dx), __fmul_rn(dy, dy)), __fmul_rn(dz, dz)));
        s1x += dx; s1y += dy; s1z += dz; s1d += dd;
        mxx += dx * dx; mxy += dx * dy; mxz += dx * dz; mxd += dx * dd;
        myy += dy * dy; myz += dy * dz; myd += dy * dd;
        mzz += dz * dz; mzd += dz * dd; mdd += dd * dd;
    }
    {
        // every query counted 4x (once per split lane) -> exact /4 after reduce
        float vals[NMOM] = {s1x, s1y, s1z, s1d,
                            mxx, mxy, mxz, mxd, myy, myz, myd, mzz, mzd, mdd};
#pragma unroll
        for (int tt = 0; tt < NMOM; ++tt) {
            float v = vals[tt];
#pragma unroll
            for (int off = 32; off > 0; off >>= 1) v += __shfl_down(v, off);
            if ((t & 63) == 0) atomicAdd(&mom[tt], v * 0.25f);
        }
    }
}

// ---------------- Kernel 2: round-8/11/12/16 verbatim --------------------
__global__ __launch_bounds__(BLK)
void out_kernel(const float* __restrict__ pos,
                const float* __restrict__ W,
                const float* __restrict__ bias,
                const float* __restrict__ gamma,
                const float* __restrict__ beta,
                const unsigned short* __restrict__ idx_in,
                const float* __restrict__ mom,
                float* __restrict__ out) {
    __shared__ float sWp[COUT][4];
    __shared__ float sbp[COUT];

    if (threadIdx.x < COUT) {
        const int o = threadIdx.x;
        double S1[4], s2v[10];
#pragma unroll
        for (int tt = 0; tt < 4; ++tt)  S1[tt]  = (double)mom[tt];
#pragma unroll
        for (int tt = 0; tt < 10; ++tt) s2v[tt] = (double)mom[4 + tt];
        const double M = (double)NB * NP * KNN;
        double mean[4];
#pragma unroll
        for (int c = 0; c < 4; ++c) mean[c] = S1[c] / M;
        double E2[4][4];
        E2[0][0] = s2v[0]; E2[0][1] = E2[1][0] = s2v[1];
        E2[0][2] = E2[2][0] = s2v[2]; E2[0][3] = E2[3][0] = s2v[3];
        E2[1][1] = s2v[4]; E2[1][2] = E2[2][1] = s2v[5];
        E2[1][3] = E2[3][1] = s2v[6];
        E2[2][2] = s2v[7]; E2[2][3] = E2[3][2] = s2v[8];
        E2[3][3] = s2v[9];
        double w[4];
#pragma unroll
        for (int c = 0; c < 4; ++c) w[c] = (double)W[o * 4 + c];
        const double bo = (double)bias[o];
        double mu = bo;
#pragma unroll
        for (int c = 0; c < 4; ++c) mu += w[c] * mean[c];
        double var = 0.0;
#pragma unroll
        for (int c = 0; c < 4; ++c)
#pragma unroll
            for (int c2 = 0; c2 < 4; ++c2)
                var += w[c] * w[c2] * (E2[c][c2] / M - mean[c] * mean[c2]);
        const double scale = (double)gamma[o] / sqrt(var + 1e-5);
#pragma unroll
        for (int c = 0; c < 4; ++c) sWp[o][c] = (float)(w[c] * scale);
        sbp[o] = (float)((bo - mu) * scale + (double)beta[o]);
    }
    __syncthreads();

    const int t  = threadIdx.x;
    const int gq = blockIdx.x * (BLK / 4) + (t >> 2);  // global query
    const int b  = gq / NP, n = gq % NP;
    const int c0 = (t & 3) * 16;                       // my 16 channels
    const float* pb = pos + (size_t)b * NP * 3;
    const float qx = pb[3 * n], qy = pb[3 * n + 1], qz = pb[3 * n + 2];

    float fx[KNN], fy[KNN], fz[KNN], fd[KNN];
    const unsigned short* ip = idx_in + (size_t)gq * KNN;
#pragma unroll
    for (int j = 0; j < KNN; ++j) {
        const int m = ip[j];
        const float dx = __fsub_rn(pb[3 * m], qx);
        const float dy = __fsub_rn(pb[3 * m + 1], qy);
        const float dz = __fsub_rn(pb[3 * m + 2], qz);
        fx[j] = dx; fy[j] = dy; fz[j] = dz;
        fd[j] = sqrtf(__fadd_rn(
            __fadd_rn(__fmul_rn(dx, dx), __fmul_rn(dy, dy)), __fmul_rn(dz, dz)));
    }

    float* ob = out + (size_t)gq * COUT + c0;
    const float inv = 1.0f / (float)KNN;
#pragma unroll
    for (int o = 0; o < 16; o += 4) {
        float acc[4];
#pragma unroll
        for (int qq = 0; qq < 4; ++qq) {
            const float w0 = sWp[c0 + o + qq][0], w1 = sWp[c0 + o + qq][1];
            const float w2 = sWp[c0 + o + qq][2], w3 = sWp[c0 + o + qq][3];
            const float bb = sbp[c0 + o + qq];
            float a = 0.f;
#pragma unroll
            for (int j = 0; j < KNN; ++j) {
                float y = fmaf(fx[j], w0,
                          fmaf(fy[j], w1, fmaf(fz[j], w2, fmaf(fd[j], w3, bb))));
                a += fmaxf(y, 0.f);
            }
            acc[qq] = a * inv;
        }
        float4 p = {acc[0], acc[1], acc[2], acc[3]};
        *reinterpret_cast<float4*>(ob + o) = p;
    }
}

extern "C" void kernel_launch(void* const* d_in, const int* in_sizes, int n_in,
                              void* d_out, int out_size, void* d_ws, size_t ws_size,
                              hipStream_t stream) {
    (void)in_sizes; (void)n_in; (void)out_size; (void)ws_size;
    const float* pos   = (const float*)d_in[1];   // d_in[0] = x (unused by math)
    const float* W     = (const float*)d_in[2];
    const float* bias  = (const float*)d_in[3];
    const float* gamma = (const float*)d_in[4];
    const float* beta  = (const float*)d_in[5];
    float* out = (float*)d_out;

    float* mom = (float*)d_ws;                                   // 14 floats
    unsigned short* idxws = (unsigned short*)((char*)d_ws + 64); // 1.31 MB

    hipMemsetAsync(mom, 0, NMOM * sizeof(float), stream);
    knn_kernel<<<NBLK1, BLK, 0, stream>>>(pos, idxws, mom);
    out_kernel<<<NBLK2, BLK, 0, stream>>>(pos, W, bias, gamma, beta,
                                          idxws, mom, out);
}

// Round 19
// 295.922 us; speedup vs baseline: 3.2971x; 2.0265x over previous
//
#include <hip/hip_runtime.h>

#define NB    8       // batches
#define NP    4096    // points per batch
#define KNN   20      // neighbors
#define COUT  64      // output channels
#define S     4       // candidate splits per query (r16-verified config)
#define BLK   256     // threads per block (4 waves)
#define QPB   (BLK / S)          // 64 queries per block
#define BPB   (NP / QPB)         // 64 blocks per batch
#define NBLK1 (NB * BPB)         // 512 blocks
#define NBLK2 ((NB * NP * 4) / BLK)   // 512 blocks (4 threads per query)
#define NMOM  14
#define MSTR  16      // moment stride in floats: 64 B = one cache line per moment
#define LCAP  32      // padded list length for bitonic merge
#define FBIG  3.402823466e38f

typedef unsigned long long u64;
typedef unsigned int u32;

// strict-< sorted insert (ascending), insert-after-equals == lax.top_k's
// lowest-index-first tie-break (verified rounds 4/6/8/11/12/16/18). FBIG -> no-op.
__device__ __forceinline__ void ins20(float d, u32 mi,
                                      float* __restrict__ bd,
                                      u32* __restrict__ bi) {
#pragma unroll
    for (int j = KNN - 1; j >= 1; --j) {
        const bool sh  = d < bd[j - 1];
        const bool in_ = !sh && (d < bd[j]);
        bi[j] = sh ? bi[j - 1] : (in_ ? mi : bi[j]);
        bd[j] = fminf(fmaxf(bd[j - 1], d), bd[j]);   // med3
    }
    if (d < bd[0]) { bi[0] = mi; bd[0] = d; }
}

// ---------------- Kernel 1: KNN (r18 + per-line moment atomics) ----------
__global__ __launch_bounds__(BLK, 2)
void knn_kernel(const float* __restrict__ pos,
                unsigned short* __restrict__ idx_out,
                float* __restrict__ mom) {
    __shared__ float4 sp[NP];                      // 64 KB: (x, y, z, csq)

    const int b = blockIdx.x / BPB;
    const int t = threadIdx.x;
    const int s = t & (S - 1);                     // my split
    const int n = (blockIdx.x % BPB) * QPB + (t >> 2);   // my query
    const float* pb = pos + (size_t)b * NP * 3;

    // stage pos[b]; csq computed with the reference's exact op sequence
    for (int i = t; i < NP; i += BLK) {
        const float x = pb[3 * i], y = pb[3 * i + 1], z = pb[3 * i + 2];
        const float csq = __fadd_rn(
            __fadd_rn(__fmul_rn(x, x), __fmul_rn(y, y)), __fmul_rn(z, z));
        sp[i] = make_float4(x, y, z, csq);
    }
    __syncthreads();

    const float4 q = sp[n];                        // qx,qy,qz,qsq (same bits)

    // ---- sample phase: tight certified initial bound (r18-verified) ----
    float sd0 = FBIG, sd1 = FBIG, sd2 = FBIG, sd3 = FBIG, sd4 = FBIG;
#pragma unroll 4
    for (int i = 0; i < NP / S; i += 4) {
        const int m = (i << 2) | s;
        const float4 c = sp[m];
        const float dot = fmaf(q.z, c.z, fmaf(q.y, c.y, __fmul_rn(q.x, c.x)));
        const float d2  = __fsub_rn(__fadd_rn(q.w, c.w), __fmul_rn(2.0f, dot));
        if (m != n && d2 < sd4) {                  // 5-deep med3 insert (values)
            sd4 = fminf(fmaxf(sd3, d2), sd4);
            sd3 = fminf(fmaxf(sd2, d2), sd3);
            sd2 = fminf(fmaxf(sd1, d2), sd2);
            sd1 = fminf(fmaxf(sd0, d2), sd1);
            sd0 = fminf(sd0, d2);
        }
    }
    float gb = sd4;                                // my 5th-smallest sample
    gb = fmaxf(gb, __shfl_xor(gb, 1));             // group-max -> certified-20
    gb = fmaxf(gb, __shfl_xor(gb, 2));

    float bd[KNN];
    u32   bi[KNN];
#pragma unroll
    for (int j = 0; j < KNN; ++j) { bd[j] = FBIG; bi[j] = 0xFFFu; }
    float p0d = 0.f, p1d = 0.f, p2d = 0.f, p3d = 0.f;
    u32   p0i = 0, p1i = 0, p2i = 0, p3i = 0;
    int   cnt = 0;

#pragma unroll 2
    for (int i = 0; i < NP / S; ++i) {
        const int m = (i << 2) | s;
        const float4 c = sp[m];                    // 4 distinct addrs: broadcast
        const float dot = fmaf(q.z, c.z, fmaf(q.y, c.y, __fmul_rn(q.x, c.x)));
        const float d2  = __fsub_rn(__fadd_rn(q.w, c.w), __fmul_rn(2.0f, dot));
        // <=: rejection requires 20 STRICTLY better witnesses (index-free);
        // boundary cases flow through own-lane ins20 (exact). (r12/16-verified)
        const bool acc = (m != n) && (d2 <= gb);
        const bool a0 = acc && (cnt == 0), a1 = acc && (cnt == 1);
        const bool a2 = acc && (cnt == 2), a3 = acc && (cnt == 3);
        p0d = a0 ? d2 : p0d;  p0i = a0 ? (u32)m : p0i;
        p1d = a1 ? d2 : p1d;  p1i = a1 ? (u32)m : p1i;
        p2d = a2 ? d2 : p2d;  p2i = a2 ? (u32)m : p2i;
        p3d = a3 ? d2 : p3d;  p3i = a3 ? (u32)m : p3i;
        cnt += (int)acc;
        if (__ballot(cnt == 4)) {                  // amortized wave-wide flush
            ins20(cnt >= 1 ? p0d : FBIG, p0i, bd, bi);
            ins20(cnt >= 2 ? p1d : FBIG, p1i, bd, bi);
            ins20(cnt >= 3 ? p2d : FBIG, p2i, bd, bi);
            ins20(cnt >= 4 ? p3d : FBIG, p3i, bd, bi);
            cnt = 0;
            float g = bd[KNN - 1];                 // refresh group bound
            g = fminf(g, __shfl_xor(g, 1));
            g = fminf(g, __shfl_xor(g, 2));
            gb = fminf(gb, g);                     // never loosen below sample bound
        }
    }
    // drain pending
    ins20(cnt >= 1 ? p0d : FBIG, p0i, bd, bi);
    ins20(cnt >= 2 ? p1d : FBIG, p1i, bd, bi);
    ins20(cnt >= 3 ? p2d : FBIG, p2i, bd, bi);
    ins20(cnt >= 4 ? p3d : FBIG, p3i, bd, bi);

    // build merge keys: order-preserving float->uint flip,
    // idx in low 12 bits = lowest-index-first ties (verified r7/8/11/12/16/18)
    u64 key[LCAP];
#pragma unroll
    for (int j = 0; j < KNN; ++j) {
        u32 fb = __float_as_uint(bd[j]);
        fb ^= (u32)((int)fb >> 31) | 0x80000000u;
        key[j] = ((u64)fb << 12) | bi[j];
    }
#pragma unroll
    for (int j = KNN; j < LCAP; ++j) key[j] = ~0ull;

    // merge 4 split lists across lanes (verified bitonic merge)
#pragma unroll
    for (int r = 1; r <= 2; r <<= 1) {
#pragma unroll
        for (int j = 0; j < LCAP / 2; ++j) {
            const int k2 = LCAP - 1 - j;
            const u64 pa = (u64)__shfl_xor((long long)key[k2], r);
            const u64 pc = (u64)__shfl_xor((long long)key[j],  r);
            key[j]  = key[j]  < pa ? key[j]  : pa;
            key[k2] = key[k2] < pc ? key[k2] : pc;
        }
#pragma unroll
        for (int d = 16; d >= 1; d >>= 1) {
#pragma unroll
            for (int j = 0; j < LCAP; ++j) {
                if ((j & d) == 0) {
                    const u64 x = key[j], y = key[j + d];
                    key[j]     = x < y ? x : y;
                    key[j + d] = x < y ? y : x;
                }
            }
        }
    }

    // static-j epilogue (verified; no dynamic reg indexing)
    unsigned short* ip = idx_out + ((size_t)b * NP + n) * KNN;
    float s1x = 0, s1y = 0, s1z = 0, s1d = 0;
    float mxx = 0, mxy = 0, mxz = 0, mxd = 0;
    float myy = 0, myz = 0, myd = 0;
    float mzz = 0, mzd = 0, mdd = 0;
#pragma unroll
    for (int j = 0; j < KNN; ++j) {
        const int m = (int)(key[j] & 0xFFFull);
        if ((j & 3) == s) ip[j] = (unsigned short)m;   // one lane per j
        const float4 c = sp[m];
        const float dx = __fsub_rn(c.x, q.x);
        const float dy = __fsub_rn(c.y, q.y);
        const float dz = __fsub_rn(c.z, q.z);
        const float dd = sqrtf(__fadd_rn(
            __fadd_rn(__fmul_rn(dx, dx), __fmul_rn(dy, dy)), __fmul_rn(dz, dz)));
        s1x += dx; s1y += dy; s1z += dz; s1d += dd;
        mxx += dx * dx; mxy += dx * dy; mxz += dx * dz; mxd += dx * dd;
        myy += dy * dy; myz += dy * dz; myd += dy * dd;
        mzz += dz * dz; mzd += dz * dd; mdd += dd * dd;
    }
    {
        // every query counted 4x (once per split lane) -> exact /4 after reduce.
        // ONE CHANGE vs r18: each moment gets its OWN cache line (mom[tt*16])
        // so the 2048-deep same-address atomic queues run in parallel across
        // 14 lines instead of serializing on one line.
        float vals[NMOM] = {s1x, s1y, s1z, s1d,
                            mxx, mxy, mxz, mxd, myy, myz, myd, mzz, mzd, mdd};
#pragma unroll
        for (int tt = 0; tt < NMOM; ++tt) {
            float v = vals[tt];
#pragma unroll
            for (int off = 32; off > 0; off >>= 1) v += __shfl_down(v, off);
            if ((t & 63) == 0) atomicAdd(&mom[tt * MSTR], v * 0.25f);
        }
    }
}

// ---------------- Kernel 2: r18 verbatim, strided mom reads --------------
__global__ __launch_bounds__(BLK)
void out_kernel(const float* __restrict__ pos,
                const float* __restrict__ W,
                const float* __restrict__ bias,
                const float* __restrict__ gamma,
                const float* __restrict__ beta,
                const unsigned short* __restrict__ idx_in,
                const float* __restrict__ mom,
                float* __restrict__ out) {
    __shared__ float sWp[COUT][4];
    __shared__ float sbp[COUT];

    if (threadIdx.x < COUT) {
        const int o = threadIdx.x;
        double S1[4], s2v[10];
#pragma unroll
        for (int tt = 0; tt < 4; ++tt)  S1[tt]  = (double)mom[tt * MSTR];
#pragma unroll
        for (int tt = 0; tt < 10; ++tt) s2v[tt] = (double)mom[(4 + tt) * MSTR];
        const double M = (double)NB * NP * KNN;
        double mean[4];
#pragma unroll
        for (int c = 0; c < 4; ++c) mean[c] = S1[c] / M;
        double E2[4][4];
        E2[0][0] = s2v[0]; E2[0][1] = E2[1][0] = s2v[1];
        E2[0][2] = E2[2][0] = s2v[2]; E2[0][3] = E2[3][0] = s2v[3];
        E2[1][1] = s2v[4]; E2[1][2] = E2[2][1] = s2v[5];
        E2[1][3] = E2[3][1] = s2v[6];
        E2[2][2] = s2v[7]; E2[2][3] = E2[3][2] = s2v[8];
        E2[3][3] = s2v[9];
        double w[4];
#pragma unroll
        for (int c = 0; c < 4; ++c) w[c] = (double)W[o * 4 + c];
        const double bo = (double)bias[o];
        double mu = bo;
#pragma unroll
        for (int c = 0; c < 4; ++c) mu += w[c] * mean[c];
        double var = 0.0;
#pragma unroll
        for (int c = 0; c < 4; ++c)
#pragma unroll
            for (int c2 = 0; c2 < 4; ++c2)
                var += w[c] * w[c2] * (E2[c][c2] / M - mean[c] * mean[c2]);
        const double scale = (double)gamma[o] / sqrt(var + 1e-5);
#pragma unroll
        for (int c = 0; c < 4; ++c) sWp[o][c] = (float)(w[c] * scale);
        sbp[o] = (float)((bo - mu) * scale + (double)beta[o]);
    }
    __syncthreads();

    const int t  = threadIdx.x;
    const int gq = blockIdx.x * (BLK / 4) + (t >> 2);  // global query
    const int b  = gq / NP, n = gq % NP;
    const int c0 = (t & 3) * 16;                       // my 16 channels
    const float* pb = pos + (size_t)b * NP * 3;
    const float qx = pb[3 * n], qy = pb[3 * n + 1], qz = pb[3 * n + 2];

    float fx[KNN], fy[KNN], fz[KNN], fd[KNN];
    const unsigned short* ip = idx_in + (size_t)gq * KNN;
#pragma unroll
    for (int j = 0; j < KNN; ++j) {
        const int m = ip[j];
        const float dx = __fsub_rn(pb[3 * m], qx);
        const float dy = __fsub_rn(pb[3 * m + 1], qy);
        const float dz = __fsub_rn(pb[3 * m + 2], qz);
        fx[j] = dx; fy[j] = dy; fz[j] = dz;
        fd[j] = sqrtf(__fadd_rn(
            __fadd_rn(__fmul_rn(dx, dx), __fmul_rn(dy, dy)), __fmul_rn(dz, dz)));
    }

    float* ob = out + (size_t)gq * COUT + c0;
    const float inv = 1.0f / (float)KNN;
#pragma unroll
    for (int o = 0; o < 16; o += 4) {
        float acc[4];
#pragma unroll
        for (int qq = 0; qq < 4; ++qq) {
            const float w0 = sWp[c0 + o + qq][0], w1 = sWp[c0 + o + qq][1];
            const float w2 = sWp[c0 + o + qq][2], w3 = sWp[c0 + o + qq][3];
            const float bb = sbp[c0 + o + qq];
            float a = 0.f;
#pragma unroll
            for (int j = 0; j < KNN; ++j) {
                float y = fmaf(fx[j], w0,
                          fmaf(fy[j], w1, fmaf(fz[j], w2, fmaf(fd[j], w3, bb))));
                a += fmaxf(y, 0.f);
            }
            acc[qq] = a * inv;
        }
        float4 p = {acc[0], acc[1], acc[2], acc[3]};
        *reinterpret_cast<float4*>(ob + o) = p;
    }
}

extern "C" void kernel_launch(void* const* d_in, const int* in_sizes, int n_in,
                              void* d_out, int out_size, void* d_ws, size_t ws_size,
                              hipStream_t stream) {
    (void)in_sizes; (void)n_in; (void)out_size; (void)ws_size;
    const float* pos   = (const float*)d_in[1];   // d_in[0] = x (unused by math)
    const float* W     = (const float*)d_in[2];
    const float* bias  = (const float*)d_in[3];
    const float* gamma = (const float*)d_in[4];
    const float* beta  = (const float*)d_in[5];
    float* out = (float*)d_out;

    float* mom = (float*)d_ws;                                    // 14 x 64 B
    unsigned short* idxws = (unsigned short*)((char*)d_ws + 1024); // 1.31 MB

    hipMemsetAsync(mom, 0, NMOM * MSTR * sizeof(float), stream);
    knn_kernel<<<NBLK1, BLK, 0, stream>>>(pos, idxws, mom);
    out_kernel<<<NBLK2, BLK, 0, stream>>>(pos, W, bias, gamma, beta,
                                          idxws, mom, out);
}